// Round 1
// baseline (1335.170 us; speedup 1.0000x reference)
//
#include <hip/hip_runtime.h>
#include <hip/hip_bf16.h>

#define N_NODES 500000
#define N_ELEM  2000000

// ws layout:
//   [0, 64)                         : double accum[8]
//       accum[0] = sum(E*A)
//       accum[1] = sum(E*I/L)
//       accum[2] = sum_sq_F (raw, masked by free_disp)
//       accum[3] = sum_sq_M (raw, masked by free_rot)
//       accum[4] = sum(free_disp)
//       accum[5] = sum(free_rot)
//   [64, 64 + N_NODES*3*4)          : float F_total
//   [.. , .. + N_NODES*3*4)         : float M_total

__device__ __forceinline__ float wave_reduce(float v) {
    #pragma unroll
    for (int o = 32; o > 0; o >>= 1) v += __shfl_down(v, o, 64);
    return v;
}

// block = 256 threads = 4 waves
__device__ __forceinline__ void block_reduce_add(float v, double* dst, float* sm4) {
    int lane = threadIdx.x & 63;
    int wave = threadIdx.x >> 6;
    v = wave_reduce(v);
    if (lane == 0) sm4[wave] = v;
    __syncthreads();
    if (threadIdx.x == 0) {
        float s = sm4[0] + sm4[1] + sm4[2] + sm4[3];
        atomicAdd(dst, (double)s);
    }
    __syncthreads();
}

__global__ __launch_bounds__(256) void elem_kernel(
    const float* __restrict__ pred,
    const int*   __restrict__ conn,
    const float* __restrict__ dirs,
    const float* __restrict__ L_,
    const float* __restrict__ E_,
    const float* __restrict__ A_,
    const float* __restrict__ I_,
    float* __restrict__ F_total,
    float* __restrict__ M_total,
    double* __restrict__ accum)
{
    __shared__ float sm4[4];
    int e = blockIdx.x * blockDim.x + threadIdx.x;
    float ea = 0.f, eil = 0.f;
    if (e < N_ELEM) {
        int ni = conn[2 * e];
        int nj = conn[2 * e + 1];
        float x0 = dirs[3 * e + 0], x1 = dirs[3 * e + 1], x2 = dirs[3 * e + 2];

        // local axes: ref = |x1|>0.99 ? (0,0,1) : (0,1,0)
        bool par = fabsf(x1) > 0.99f;
        float r1 = par ? 0.f : 1.f;
        float r2 = par ? 1.f : 0.f;
        // z = cross(x, ref); (r0 = 0)
        float z0 = x1 * r2 - x2 * r1;
        float z1 = x2 * 0.f - x0 * r2;
        float z2 = x0 * r1 - x1 * 0.f;
        float zn = fmaxf(sqrtf(z0 * z0 + z1 * z1 + z2 * z2), 1e-8f);
        float izn = 1.f / zn;
        z0 *= izn; z1 *= izn; z2 *= izn;
        // y = cross(z, x)
        float y0 = z1 * x2 - z2 * x1;
        float y1 = z2 * x0 - z0 * x2;
        float y2 = z0 * x1 - z1 * x0;
        float yn = fmaxf(sqrtf(y0 * y0 + y1 * y1 + y2 * y2), 1e-8f);
        float iyn = 1.f / yn;
        y0 *= iyn; y1 *= iyn; y2 *= iyn;

        const float* pi = pred + 6l * ni;
        const float* pj = pred + 6l * nj;
        float du0 = pj[0] - pi[0];
        float du1 = pj[1] - pi[1];
        float du2 = pj[2] - pi[2];
        float ti0 = pi[3], ti1 = pi[4], ti2 = pi[5];
        float tj0 = pj[3], tj1 = pj[4], tj2 = pj[5];

        float L = L_[e], E = E_[e], A = A_[e], I = I_[e];
        float EA = E * A;
        float EI = E * I;
        float invL = 1.f / L;
        float invL2 = invL * invL;
        float invL3 = invL2 * invL;

        float axial = du0 * x0 + du1 * x1 + du2 * x2;
        float Naxial = EA * invL * axial;

        float k12 = 12.f * EI * invL3;
        float k6  = 6.f * EI * invL2;
        float kL  = EI * invL;

        float dwz = du0 * z0 + du1 * z1 + du2 * z2;
        float tyi = ti0 * y0 + ti1 * y1 + ti2 * y2;
        float tyj = tj0 * y0 + tj1 * y1 + tj2 * y2;
        float Vz  = k12 * dwz + k6 * (tyi + tyj);
        float Myi = k6 * dwz + kL * (2.f * tyi + tyj);
        float Myj = k6 * dwz + kL * (tyi + 2.f * tyj);

        float dwy = du0 * y0 + du1 * y1 + du2 * y2;
        float tzi = ti0 * z0 + ti1 * z1 + ti2 * z2;
        float tzj = tj0 * z0 + tj1 * z1 + tj2 * z2;
        float Vy  = k12 * dwy + k6 * (tzi + tzj);
        float Mzi = k6 * dwy + kL * (2.f * tzi + tzj);
        float Mzj = k6 * dwy + kL * (tzi + 2.f * tzj);

        float F0 = Naxial * x0 + Vz * z0 + Vy * y0;
        float F1 = Naxial * x1 + Vz * z1 + Vy * y1;
        float F2 = Naxial * x2 + Vz * z2 + Vy * y2;

        float Mi0 = Myi * y0 + Mzi * z0;
        float Mi1 = Myi * y1 + Mzi * z1;
        float Mi2 = Myi * y2 + Mzi * z2;
        float Mj0 = Myj * y0 + Mzj * z0;
        float Mj1 = Myj * y1 + Mzj * z1;
        float Mj2 = Myj * y2 + Mzj * z2;

        atomicAdd(&F_total[3l * ni + 0],  F0);
        atomicAdd(&F_total[3l * ni + 1],  F1);
        atomicAdd(&F_total[3l * ni + 2],  F2);
        atomicAdd(&F_total[3l * nj + 0], -F0);
        atomicAdd(&F_total[3l * nj + 1], -F1);
        atomicAdd(&F_total[3l * nj + 2], -F2);
        atomicAdd(&M_total[3l * ni + 0], Mi0);
        atomicAdd(&M_total[3l * ni + 1], Mi1);
        atomicAdd(&M_total[3l * ni + 2], Mi2);
        atomicAdd(&M_total[3l * nj + 0], Mj0);
        atomicAdd(&M_total[3l * nj + 1], Mj1);
        atomicAdd(&M_total[3l * nj + 2], Mj2);

        ea  = EA;
        eil = EI * invL;
    }
    block_reduce_add(ea,  &accum[0], sm4);
    block_reduce_add(eil, &accum[1], sm4);
}

__global__ __launch_bounds__(256) void node_kernel(
    const float* __restrict__ F_total,
    const float* __restrict__ M_total,
    const float* __restrict__ line_load,
    const float* __restrict__ bc_disp,
    const float* __restrict__ bc_rot,
    double* __restrict__ accum)
{
    __shared__ float sm4[4];
    int n = blockIdx.x * blockDim.x + threadIdx.x;
    float sqF = 0.f, sqM = 0.f, fd = 0.f, fr = 0.f;
    if (n < N_NODES) {
        fd = (bc_disp[n] < 0.5f) ? 1.f : 0.f;
        fr = (bc_rot[n]  < 0.5f) ? 1.f : 0.f;
        float Fr0 = F_total[3l * n + 0] + line_load[3l * n + 0];
        float Fr1 = F_total[3l * n + 1] + line_load[3l * n + 1];
        float Fr2 = F_total[3l * n + 2] + line_load[3l * n + 2];
        float M0 = M_total[3l * n + 0];
        float M1 = M_total[3l * n + 1];
        float M2 = M_total[3l * n + 2];
        sqF = fd * (Fr0 * Fr0 + Fr1 * Fr1 + Fr2 * Fr2);
        sqM = fr * (M0 * M0 + M1 * M1 + M2 * M2);
    }
    block_reduce_add(sqF, &accum[2], sm4);
    block_reduce_add(sqM, &accum[3], sm4);
    block_reduce_add(fd,  &accum[4], sm4);
    block_reduce_add(fr,  &accum[5], sm4);
}

__global__ void final_kernel(const double* __restrict__ accum,
                             float* __restrict__ out)
{
    double F_char = fmax(accum[0] / (double)N_ELEM, 1.0);
    double M_char = fmax(accum[1] / (double)N_ELEM, 1.0);
    double lf = accum[2] / (F_char * F_char) / fmax(accum[4] * 3.0, 1.0);
    double lm = accum[3] / (M_char * M_char) / fmax(accum[5] * 3.0, 1.0);
    out[0] = (float)(lf + lm);
}

extern "C" void kernel_launch(void* const* d_in, const int* in_sizes, int n_in,
                              void* d_out, int out_size, void* d_ws, size_t ws_size,
                              hipStream_t stream) {
    const float* pred      = (const float*)d_in[0];
    const int*   conn      = (const int*)  d_in[1];
    const float* dirs      = (const float*)d_in[2];
    const float* lens      = (const float*)d_in[3];
    const float* prop_E    = (const float*)d_in[4];
    const float* prop_A    = (const float*)d_in[5];
    const float* prop_I    = (const float*)d_in[6];
    const float* line_load = (const float*)d_in[7];
    const float* bc_disp   = (const float*)d_in[8];
    const float* bc_rot    = (const float*)d_in[9];

    double* accum   = (double*)d_ws;
    float*  F_total = (float*)((char*)d_ws + 64);
    float*  M_total = F_total + (size_t)N_NODES * 3;

    size_t zero_bytes = 64 + 2ull * N_NODES * 3 * sizeof(float);
    hipMemsetAsync(d_ws, 0, zero_bytes, stream);

    int be = (N_ELEM + 255) / 256;
    elem_kernel<<<be, 256, 0, stream>>>(pred, conn, dirs, lens, prop_E, prop_A,
                                        prop_I, F_total, M_total, accum);

    int bn = (N_NODES + 255) / 256;
    node_kernel<<<bn, 256, 0, stream>>>(F_total, M_total, line_load, bc_disp,
                                        bc_rot, accum);

    final_kernel<<<1, 1, 0, stream>>>(accum, (float*)d_out);
}

// Round 2
// 496.568 us; speedup vs baseline: 2.6888x; 2.6888x over previous
//
#include <hip/hip_runtime.h>
#include <hip/hip_bf16.h>

#define N_NODES 500000
#define N_ELEM  2000000

#define BSHIFT 9                       // 512 nodes per bucket
#define NPB    (1 << BSHIFT)           // 512
#define NB     ((N_NODES + NPB - 1) >> BSHIFT)  // 977

// ws layout (bucket path):
//   [0,64)        double accum[8]
//                  accum[0]=sum(E*A) accum[1]=sum(E*I/L)
//                  accum[2]=sum_sq_F accum[3]=sum_sq_M
//                  accum[4]=sum(free_disp) accum[5]=sum(free_rot)
//   [1024, +4*NB)  int bucket_cnt[NB]
//   [8192, +4*NB)  int bucket_cur[NB]
//   [16384,+4*(NB+1)) int bucket_off[NB+1]
//   [32768, +16MB) uint entries[2*N_ELEM]
#define WS_NEED (32768ull + 4ull * 2 * N_ELEM)

__device__ __forceinline__ float wave_reduce(float v) {
    #pragma unroll
    for (int o = 32; o > 0; o >>= 1) v += __shfl_down(v, o, 64);
    return v;
}

// block = 256 threads = 4 waves
__device__ __forceinline__ void block_reduce_add(float v, double* dst, float* sm4) {
    int lane = threadIdx.x & 63;
    int wave = threadIdx.x >> 6;
    v = wave_reduce(v);
    if (lane == 0) sm4[wave] = v;
    __syncthreads();
    if (threadIdx.x == 0) {
        float s = sm4[0] + sm4[1] + sm4[2] + sm4[3];
        atomicAdd(dst, (double)s);
    }
    __syncthreads();
}

// ---------------- full per-end beam math ----------------
// given element e and end (0=i,1=j), produce the F contribution (signed)
// and the M contribution for that end's node.
__device__ __forceinline__ void beam_contrib(
    int e, int end, int ni, int nj,
    const float* __restrict__ pred,
    const float* __restrict__ dirs,
    const float* __restrict__ L_, const float* __restrict__ E_,
    const float* __restrict__ A_, const float* __restrict__ I_,
    float& Fc0, float& Fc1, float& Fc2,
    float& Mc0, float& Mc1, float& Mc2)
{
    float x0 = dirs[3 * e + 0], x1 = dirs[3 * e + 1], x2 = dirs[3 * e + 2];

    bool par = fabsf(x1) > 0.99f;
    float r1 = par ? 0.f : 1.f;
    float r2 = par ? 1.f : 0.f;
    float z0 = x1 * r2 - x2 * r1;
    float z1 = -x0 * r2;
    float z2 = x0 * r1;
    float zn = fmaxf(sqrtf(z0 * z0 + z1 * z1 + z2 * z2), 1e-8f);
    float izn = 1.f / zn;
    z0 *= izn; z1 *= izn; z2 *= izn;
    float y0 = z1 * x2 - z2 * x1;
    float y1 = z2 * x0 - z0 * x2;
    float y2 = z0 * x1 - z1 * x0;
    float yn = fmaxf(sqrtf(y0 * y0 + y1 * y1 + y2 * y2), 1e-8f);
    float iyn = 1.f / yn;
    y0 *= iyn; y1 *= iyn; y2 *= iyn;

    const float* pi = pred + 6l * ni;
    const float* pj = pred + 6l * nj;
    float2 a0 = *(const float2*)(pi + 0);
    float2 a1 = *(const float2*)(pi + 2);
    float2 a2 = *(const float2*)(pi + 4);
    float2 b0 = *(const float2*)(pj + 0);
    float2 b1 = *(const float2*)(pj + 2);
    float2 b2 = *(const float2*)(pj + 4);
    float du0 = b0.x - a0.x;
    float du1 = b0.y - a0.y;
    float du2 = b1.x - a1.x;
    float ti0 = a1.y, ti1 = a2.x, ti2 = a2.y;
    float tj0 = b1.y, tj1 = b2.x, tj2 = b2.y;

    float L = L_[e], E = E_[e], A = A_[e], I = I_[e];
    float EA = E * A;
    float EI = E * I;
    float invL = 1.f / L;
    float invL2 = invL * invL;
    float invL3 = invL2 * invL;

    float axial = du0 * x0 + du1 * x1 + du2 * x2;
    float Naxial = EA * invL * axial;

    float k12 = 12.f * EI * invL3;
    float k6  = 6.f * EI * invL2;
    float kL  = EI * invL;

    float dwz = du0 * z0 + du1 * z1 + du2 * z2;
    float tyi = ti0 * y0 + ti1 * y1 + ti2 * y2;
    float tyj = tj0 * y0 + tj1 * y1 + tj2 * y2;
    float Vz  = k12 * dwz + k6 * (tyi + tyj);
    float Myi = k6 * dwz + kL * (2.f * tyi + tyj);
    float Myj = k6 * dwz + kL * (tyi + 2.f * tyj);

    float dwy = du0 * y0 + du1 * y1 + du2 * y2;
    float tzi = ti0 * z0 + ti1 * z1 + ti2 * z2;
    float tzj = tj0 * z0 + tj1 * z1 + tj2 * z2;
    float Vy  = k12 * dwy + k6 * (tzi + tzj);
    float Mzi = k6 * dwy + kL * (2.f * tzi + tzj);
    float Mzj = k6 * dwy + kL * (tzi + 2.f * tzj);

    float F0 = Naxial * x0 + Vz * z0 + Vy * y0;
    float F1 = Naxial * x1 + Vz * z1 + Vy * y1;
    float F2 = Naxial * x2 + Vz * z2 + Vy * y2;

    float sgn = end ? -1.f : 1.f;
    Fc0 = sgn * F0; Fc1 = sgn * F1; Fc2 = sgn * F2;
    float My = end ? Myj : Myi;
    float Mz = end ? Mzj : Mzi;
    Mc0 = My * y0 + Mz * z0;
    Mc1 = My * y1 + Mz * z1;
    Mc2 = My * y2 + Mz * z2;
}

// ---------------- bucket path kernels ----------------

__global__ __launch_bounds__(256) void count_kernel(
    const int* __restrict__ conn,
    const float* __restrict__ L_, const float* __restrict__ E_,
    const float* __restrict__ A_, const float* __restrict__ I_,
    int* __restrict__ cnt, double* __restrict__ accum)
{
    __shared__ int bins[NB];
    __shared__ float sm4[4];
    for (int i = threadIdx.x; i < NB; i += 256) bins[i] = 0;
    __syncthreads();

    int per = (N_ELEM + gridDim.x - 1) / gridDim.x;
    int e0 = blockIdx.x * per;
    int e1 = min(e0 + per, N_ELEM);
    const int2* c2 = (const int2*)conn;

    float ea = 0.f, eil = 0.f;
    for (int e = e0 + threadIdx.x; e < e1; e += 256) {
        int2 c = c2[e];
        atomicAdd(&bins[c.x >> BSHIFT], 1);
        atomicAdd(&bins[c.y >> BSHIFT], 1);
        float Ev = E_[e];
        ea  += Ev * A_[e];
        eil += Ev * I_[e] / L_[e];
    }
    __syncthreads();
    for (int i = threadIdx.x; i < NB; i += 256) {
        int c = bins[i];
        if (c) atomicAdd(&cnt[i], c);
    }
    block_reduce_add(ea,  &accum[0], sm4);
    block_reduce_add(eil, &accum[1], sm4);
}

__global__ __launch_bounds__(1024) void scan_kernel(
    const int* __restrict__ cnt,
    int* __restrict__ cur, int* __restrict__ off)
{
    __shared__ int s[1024];
    int tid = threadIdx.x;
    int v = (tid < NB) ? cnt[tid] : 0;
    s[tid] = v;
    __syncthreads();
    for (int o = 1; o < 1024; o <<= 1) {
        int t = (tid >= o) ? s[tid - o] : 0;
        __syncthreads();
        s[tid] += t;
        __syncthreads();
    }
    int excl = s[tid] - v;
    if (tid < NB) { off[tid] = excl; cur[tid] = excl; }
    if (tid == 1023) off[NB] = s[1023];
}

__global__ __launch_bounds__(256) void scatter_kernel(
    const int* __restrict__ conn,
    int* __restrict__ cur, unsigned int* __restrict__ entries)
{
    __shared__ int bins[NB];
    for (int i = threadIdx.x; i < NB; i += 256) bins[i] = 0;
    __syncthreads();

    int per = (N_ELEM + gridDim.x - 1) / gridDim.x;
    int e0 = blockIdx.x * per;
    int e1 = min(e0 + per, N_ELEM);
    const int2* c2 = (const int2*)conn;

    for (int e = e0 + threadIdx.x; e < e1; e += 256) {
        int2 c = c2[e];
        atomicAdd(&bins[c.x >> BSHIFT], 1);
        atomicAdd(&bins[c.y >> BSHIFT], 1);
    }
    __syncthreads();
    for (int i = threadIdx.x; i < NB; i += 256) {
        int c = bins[i];
        bins[i] = c ? atomicAdd(&cur[i], c) : 0;
    }
    __syncthreads();
    for (int e = e0 + threadIdx.x; e < e1; e += 256) {
        int2 c = c2[e];
        int p0 = atomicAdd(&bins[c.x >> BSHIFT], 1);
        entries[p0] = ((unsigned int)e << 1);
        int p1 = atomicAdd(&bins[c.y >> BSHIFT], 1);
        entries[p1] = ((unsigned int)e << 1) | 1u;
    }
}

__global__ __launch_bounds__(256) void bucket_kernel(
    const float* __restrict__ pred,
    const int* __restrict__ conn,
    const float* __restrict__ dirs,
    const float* __restrict__ L_, const float* __restrict__ E_,
    const float* __restrict__ A_, const float* __restrict__ I_,
    const unsigned int* __restrict__ entries,
    const int* __restrict__ off,
    const float* __restrict__ line_load,
    const float* __restrict__ bc_disp,
    const float* __restrict__ bc_rot,
    double* __restrict__ accum)
{
    __shared__ float accF[NPB * 3];
    __shared__ float accM[NPB * 3];
    __shared__ float sm4[4];
    int b = blockIdx.x;
    for (int i = threadIdx.x; i < NPB * 3; i += 256) { accF[i] = 0.f; accM[i] = 0.f; }
    __syncthreads();

    int s0 = off[b], s1 = off[b + 1];
    const int2* c2 = (const int2*)conn;
    int nbase = b << BSHIFT;

    for (int k = s0 + threadIdx.x; k < s1; k += 256) {
        unsigned int ent = entries[k];
        int e = (int)(ent >> 1);
        int end = (int)(ent & 1u);
        int2 c = c2[e];
        float F0, F1, F2, M0, M1, M2;
        beam_contrib(e, end, c.x, c.y, pred, dirs, L_, E_, A_, I_,
                     F0, F1, F2, M0, M1, M2);
        int node = end ? c.y : c.x;
        int nl = (node - nbase) * 3;
        atomicAdd(&accF[nl + 0], F0);
        atomicAdd(&accF[nl + 1], F1);
        atomicAdd(&accF[nl + 2], F2);
        atomicAdd(&accM[nl + 0], M0);
        atomicAdd(&accM[nl + 1], M1);
        atomicAdd(&accM[nl + 2], M2);
    }
    __syncthreads();

    float sqF = 0.f, sqM = 0.f, fd = 0.f, fr = 0.f;
    for (int nl = threadIdx.x; nl < NPB; nl += 256) {
        int n = nbase + nl;
        if (n < N_NODES) {
            float fdv = (bc_disp[n] < 0.5f) ? 1.f : 0.f;
            float frv = (bc_rot[n]  < 0.5f) ? 1.f : 0.f;
            float Fr0 = accF[nl * 3 + 0] + line_load[3l * n + 0];
            float Fr1 = accF[nl * 3 + 1] + line_load[3l * n + 1];
            float Fr2 = accF[nl * 3 + 2] + line_load[3l * n + 2];
            float M0 = accM[nl * 3 + 0];
            float M1 = accM[nl * 3 + 1];
            float M2 = accM[nl * 3 + 2];
            sqF += fdv * (Fr0 * Fr0 + Fr1 * Fr1 + Fr2 * Fr2);
            sqM += frv * (M0 * M0 + M1 * M1 + M2 * M2);
            fd += fdv;
            fr += frv;
        }
    }
    block_reduce_add(sqF, &accum[2], sm4);
    block_reduce_add(sqM, &accum[3], sm4);
    block_reduce_add(fd,  &accum[4], sm4);
    block_reduce_add(fr,  &accum[5], sm4);
}

__global__ void final_kernel(const double* __restrict__ accum,
                             float* __restrict__ out)
{
    double F_char = fmax(accum[0] / (double)N_ELEM, 1.0);
    double M_char = fmax(accum[1] / (double)N_ELEM, 1.0);
    double lf = accum[2] / (F_char * F_char) / fmax(accum[4] * 3.0, 1.0);
    double lm = accum[3] / (M_char * M_char) / fmax(accum[5] * 3.0, 1.0);
    out[0] = (float)(lf + lm);
}

// ---------------- fallback (round-1 atomic path) ----------------

__global__ __launch_bounds__(256) void elem_kernel_fb(
    const float* __restrict__ pred,
    const int*   __restrict__ conn,
    const float* __restrict__ dirs,
    const float* __restrict__ L_, const float* __restrict__ E_,
    const float* __restrict__ A_, const float* __restrict__ I_,
    float* __restrict__ F_total, float* __restrict__ M_total,
    double* __restrict__ accum)
{
    __shared__ float sm4[4];
    int e = blockIdx.x * blockDim.x + threadIdx.x;
    float ea = 0.f, eil = 0.f;
    if (e < N_ELEM) {
        int ni = conn[2 * e], nj = conn[2 * e + 1];
        float F0, F1, F2, Mi0, Mi1, Mi2, Mj0, Mj1, Mj2;
        beam_contrib(e, 0, ni, nj, pred, dirs, L_, E_, A_, I_, F0, F1, F2, Mi0, Mi1, Mi2);
        float G0, G1, G2;
        beam_contrib(e, 1, ni, nj, pred, dirs, L_, E_, A_, I_, G0, G1, G2, Mj0, Mj1, Mj2);
        atomicAdd(&F_total[3l * ni + 0], F0);
        atomicAdd(&F_total[3l * ni + 1], F1);
        atomicAdd(&F_total[3l * ni + 2], F2);
        atomicAdd(&F_total[3l * nj + 0], G0);
        atomicAdd(&F_total[3l * nj + 1], G1);
        atomicAdd(&F_total[3l * nj + 2], G2);
        atomicAdd(&M_total[3l * ni + 0], Mi0);
        atomicAdd(&M_total[3l * ni + 1], Mi1);
        atomicAdd(&M_total[3l * ni + 2], Mi2);
        atomicAdd(&M_total[3l * nj + 0], Mj0);
        atomicAdd(&M_total[3l * nj + 1], Mj1);
        atomicAdd(&M_total[3l * nj + 2], Mj2);
        float Ev = E_[e];
        ea  = Ev * A_[e];
        eil = Ev * I_[e] / L_[e];
    }
    block_reduce_add(ea,  &accum[0], sm4);
    block_reduce_add(eil, &accum[1], sm4);
}

__global__ __launch_bounds__(256) void node_kernel_fb(
    const float* __restrict__ F_total, const float* __restrict__ M_total,
    const float* __restrict__ line_load,
    const float* __restrict__ bc_disp, const float* __restrict__ bc_rot,
    double* __restrict__ accum)
{
    __shared__ float sm4[4];
    int n = blockIdx.x * blockDim.x + threadIdx.x;
    float sqF = 0.f, sqM = 0.f, fd = 0.f, fr = 0.f;
    if (n < N_NODES) {
        fd = (bc_disp[n] < 0.5f) ? 1.f : 0.f;
        fr = (bc_rot[n]  < 0.5f) ? 1.f : 0.f;
        float Fr0 = F_total[3l * n + 0] + line_load[3l * n + 0];
        float Fr1 = F_total[3l * n + 1] + line_load[3l * n + 1];
        float Fr2 = F_total[3l * n + 2] + line_load[3l * n + 2];
        float M0 = M_total[3l * n + 0];
        float M1 = M_total[3l * n + 1];
        float M2 = M_total[3l * n + 2];
        sqF = fd * (Fr0 * Fr0 + Fr1 * Fr1 + Fr2 * Fr2);
        sqM = fr * (M0 * M0 + M1 * M1 + M2 * M2);
    }
    block_reduce_add(sqF, &accum[2], sm4);
    block_reduce_add(sqM, &accum[3], sm4);
    block_reduce_add(fd,  &accum[4], sm4);
    block_reduce_add(fr,  &accum[5], sm4);
}

extern "C" void kernel_launch(void* const* d_in, const int* in_sizes, int n_in,
                              void* d_out, int out_size, void* d_ws, size_t ws_size,
                              hipStream_t stream) {
    const float* pred      = (const float*)d_in[0];
    const int*   conn      = (const int*)  d_in[1];
    const float* dirs      = (const float*)d_in[2];
    const float* lens      = (const float*)d_in[3];
    const float* prop_E    = (const float*)d_in[4];
    const float* prop_A    = (const float*)d_in[5];
    const float* prop_I    = (const float*)d_in[6];
    const float* line_load = (const float*)d_in[7];
    const float* bc_disp   = (const float*)d_in[8];
    const float* bc_rot    = (const float*)d_in[9];

    double* accum = (double*)d_ws;

    if (ws_size >= WS_NEED) {
        int* cnt = (int*)((char*)d_ws + 1024);
        int* cur = (int*)((char*)d_ws + 8192);
        int* off = (int*)((char*)d_ws + 16384);
        unsigned int* entries = (unsigned int*)((char*)d_ws + 32768);

        hipMemsetAsync(d_ws, 0, 8192, stream);  // accum + cnt

        count_kernel<<<256, 256, 0, stream>>>(conn, lens, prop_E, prop_A, prop_I,
                                              cnt, accum);
        scan_kernel<<<1, 1024, 0, stream>>>(cnt, cur, off);
        scatter_kernel<<<256, 256, 0, stream>>>(conn, cur, entries);
        bucket_kernel<<<NB, 256, 0, stream>>>(pred, conn, dirs, lens, prop_E,
                                              prop_A, prop_I, entries, off,
                                              line_load, bc_disp, bc_rot, accum);
    } else {
        float* F_total = (float*)((char*)d_ws + 64);
        float* M_total = F_total + (size_t)N_NODES * 3;
        hipMemsetAsync(d_ws, 0, 64 + 2ull * N_NODES * 3 * sizeof(float), stream);
        int be = (N_ELEM + 255) / 256;
        elem_kernel_fb<<<be, 256, 0, stream>>>(pred, conn, dirs, lens, prop_E,
                                               prop_A, prop_I, F_total, M_total, accum);
        int bn = (N_NODES + 255) / 256;
        node_kernel_fb<<<bn, 256, 0, stream>>>(F_total, M_total, line_load,
                                               bc_disp, bc_rot, accum);
    }
    final_kernel<<<1, 1, 0, stream>>>(accum, (float*)d_out);
}

// Round 3
// 307.758 us; speedup vs baseline: 4.3384x; 1.6135x over previous
//
#include <hip/hip_runtime.h>
#include <hip/hip_bf16.h>

#define N_NODES 500000
#define N_ELEM  2000000

#define BSHIFT 10                      // 1024 nodes per bucket
#define NPB    (1 << BSHIFT)           // 1024
#define NB     ((N_NODES + NPB - 1) >> BSHIFT)  // 489

// ws layout (payload path):
//   [0,64)            double accum[8]
//   [1024, +4*NB)     int bucket_cnt[NB]
//   [8192, +4*NB)     int bucket_cur[NB]
//   [16384,+4*(NB+1)) int bucket_off[NB+1]
//   [32768, +128MB)   float4 payload[2 * 2*N_ELEM]   (32B per entry)
#define WS_IDX  (32768ull + 4ull * 2 * N_ELEM)               // round-2 path
#define WS_PAY  (32768ull + 32ull * 2 * N_ELEM)              // payload path

__device__ __forceinline__ float wave_reduce(float v) {
    #pragma unroll
    for (int o = 32; o > 0; o >>= 1) v += __shfl_down(v, o, 64);
    return v;
}

// block = 256 threads = 4 waves
__device__ __forceinline__ void block_reduce_add(float v, double* dst, float* sm4) {
    int lane = threadIdx.x & 63;
    int wave = threadIdx.x >> 6;
    v = wave_reduce(v);
    if (lane == 0) sm4[wave] = v;
    __syncthreads();
    if (threadIdx.x == 0) {
        float s = sm4[0] + sm4[1] + sm4[2] + sm4[3];
        atomicAdd(dst, (double)s);
    }
    __syncthreads();
}

// ---------------- full element beam math (both ends at once) ----------------
__device__ __forceinline__ void beam_full(
    float x0, float x1, float x2,
    const float* __restrict__ pi, const float* __restrict__ pj,
    float L, float E, float A, float I,
    float& F0, float& F1, float& F2,
    float& Mi0, float& Mi1, float& Mi2,
    float& Mj0, float& Mj1, float& Mj2)
{
    bool par = fabsf(x1) > 0.99f;
    float r1 = par ? 0.f : 1.f;
    float r2 = par ? 1.f : 0.f;
    float z0 = x1 * r2 - x2 * r1;
    float z1 = -x0 * r2;
    float z2 = x0 * r1;
    float zn = fmaxf(sqrtf(z0 * z0 + z1 * z1 + z2 * z2), 1e-8f);
    float izn = 1.f / zn;
    z0 *= izn; z1 *= izn; z2 *= izn;
    float y0 = z1 * x2 - z2 * x1;
    float y1 = z2 * x0 - z0 * x2;
    float y2 = z0 * x1 - z1 * x0;
    float yn = fmaxf(sqrtf(y0 * y0 + y1 * y1 + y2 * y2), 1e-8f);
    float iyn = 1.f / yn;
    y0 *= iyn; y1 *= iyn; y2 *= iyn;

    float2 a0 = *(const float2*)(pi + 0);
    float2 a1 = *(const float2*)(pi + 2);
    float2 a2 = *(const float2*)(pi + 4);
    float2 b0 = *(const float2*)(pj + 0);
    float2 b1 = *(const float2*)(pj + 2);
    float2 b2 = *(const float2*)(pj + 4);
    float du0 = b0.x - a0.x;
    float du1 = b0.y - a0.y;
    float du2 = b1.x - a1.x;
    float ti0 = a1.y, ti1 = a2.x, ti2 = a2.y;
    float tj0 = b1.y, tj1 = b2.x, tj2 = b2.y;

    float EA = E * A;
    float EI = E * I;
    float invL = 1.f / L;
    float invL2 = invL * invL;
    float invL3 = invL2 * invL;

    float axial = du0 * x0 + du1 * x1 + du2 * x2;
    float Naxial = EA * invL * axial;

    float k12 = 12.f * EI * invL3;
    float k6  = 6.f * EI * invL2;
    float kL  = EI * invL;

    float dwz = du0 * z0 + du1 * z1 + du2 * z2;
    float tyi = ti0 * y0 + ti1 * y1 + ti2 * y2;
    float tyj = tj0 * y0 + tj1 * y1 + tj2 * y2;
    float Vz  = k12 * dwz + k6 * (tyi + tyj);
    float Myi = k6 * dwz + kL * (2.f * tyi + tyj);
    float Myj = k6 * dwz + kL * (tyi + 2.f * tyj);

    float dwy = du0 * y0 + du1 * y1 + du2 * y2;
    float tzi = ti0 * z0 + ti1 * z1 + ti2 * z2;
    float tzj = tj0 * z0 + tj1 * z1 + tj2 * z2;
    float Vy  = k12 * dwy + k6 * (tzi + tzj);
    float Mzi = k6 * dwy + kL * (2.f * tzi + tzj);
    float Mzj = k6 * dwy + kL * (tzi + 2.f * tzj);

    F0 = Naxial * x0 + Vz * z0 + Vy * y0;
    F1 = Naxial * x1 + Vz * z1 + Vy * y1;
    F2 = Naxial * x2 + Vz * z2 + Vy * y2;

    Mi0 = Myi * y0 + Mzi * z0;
    Mi1 = Myi * y1 + Mzi * z1;
    Mi2 = Myi * y2 + Mzi * z2;
    Mj0 = Myj * y0 + Mzj * z0;
    Mj1 = Myj * y1 + Mzj * z1;
    Mj2 = Myj * y2 + Mzj * z2;
}

// ---------------- shared kernels (count / scan) ----------------

__global__ __launch_bounds__(256) void count_kernel(
    const int* __restrict__ conn,
    const float* __restrict__ L_, const float* __restrict__ E_,
    const float* __restrict__ A_, const float* __restrict__ I_,
    int* __restrict__ cnt, double* __restrict__ accum)
{
    __shared__ int bins[NB];
    __shared__ float sm4[4];
    for (int i = threadIdx.x; i < NB; i += 256) bins[i] = 0;
    __syncthreads();

    int per = (N_ELEM + gridDim.x - 1) / gridDim.x;
    int e0 = blockIdx.x * per;
    int e1 = min(e0 + per, N_ELEM);
    const int2* c2 = (const int2*)conn;

    float ea = 0.f, eil = 0.f;
    for (int e = e0 + threadIdx.x; e < e1; e += 256) {
        int2 c = c2[e];
        atomicAdd(&bins[c.x >> BSHIFT], 1);
        atomicAdd(&bins[c.y >> BSHIFT], 1);
        float Ev = E_[e];
        ea  += Ev * A_[e];
        eil += Ev * I_[e] / L_[e];
    }
    __syncthreads();
    for (int i = threadIdx.x; i < NB; i += 256) {
        int c = bins[i];
        if (c) atomicAdd(&cnt[i], c);
    }
    block_reduce_add(ea,  &accum[0], sm4);
    block_reduce_add(eil, &accum[1], sm4);
}

__global__ __launch_bounds__(1024) void scan_kernel(
    const int* __restrict__ cnt,
    int* __restrict__ cur, int* __restrict__ off)
{
    __shared__ int s[1024];
    int tid = threadIdx.x;
    int v = (tid < NB) ? cnt[tid] : 0;
    s[tid] = v;
    __syncthreads();
    for (int o = 1; o < 1024; o <<= 1) {
        int t = (tid >= o) ? s[tid - o] : 0;
        __syncthreads();
        s[tid] += t;
        __syncthreads();
    }
    int excl = s[tid] - v;
    if (tid < NB) { off[tid] = excl; cur[tid] = excl; }
    if (tid == 1023) off[NB] = s[1023];
}

// ---------------- payload path ----------------

__global__ __launch_bounds__(256) void elem_scatter_kernel(
    const float* __restrict__ pred,
    const int* __restrict__ conn,
    const float* __restrict__ dirs,
    const float* __restrict__ L_, const float* __restrict__ E_,
    const float* __restrict__ A_, const float* __restrict__ I_,
    int* __restrict__ cur, float4* __restrict__ pay)
{
    __shared__ int bins[NB];
    for (int i = threadIdx.x; i < NB; i += 256) bins[i] = 0;
    __syncthreads();

    int per = (N_ELEM + gridDim.x - 1) / gridDim.x;
    int e0 = blockIdx.x * per;
    int e1 = min(e0 + per, N_ELEM);
    const int2* c2 = (const int2*)conn;

    for (int e = e0 + threadIdx.x; e < e1; e += 256) {
        int2 c = c2[e];
        atomicAdd(&bins[c.x >> BSHIFT], 1);
        atomicAdd(&bins[c.y >> BSHIFT], 1);
    }
    __syncthreads();
    // reserve contiguous chunks; bins becomes the running cursor
    for (int i = threadIdx.x; i < NB; i += 256) {
        int c = bins[i];
        bins[i] = c ? atomicAdd(&cur[i], c) : 0;
    }
    __syncthreads();

    for (int e = e0 + threadIdx.x; e < e1; e += 256) {
        int2 c = c2[e];
        float x0 = dirs[3 * e + 0], x1 = dirs[3 * e + 1], x2 = dirs[3 * e + 2];
        float L = L_[e], E = E_[e], A = A_[e], I = I_[e];
        float F0, F1, F2, Mi0, Mi1, Mi2, Mj0, Mj1, Mj2;
        beam_full(x0, x1, x2, pred + 6l * c.x, pred + 6l * c.y, L, E, A, I,
                  F0, F1, F2, Mi0, Mi1, Mi2, Mj0, Mj1, Mj2);

        int pi_ = atomicAdd(&bins[c.x >> BSHIFT], 1);
        int nli = c.x & (NPB - 1);
        pay[2l * pi_ + 0] = make_float4(F0, F1, F2, __int_as_float(nli));
        pay[2l * pi_ + 1] = make_float4(Mi0, Mi1, Mi2, 0.f);

        int pj_ = atomicAdd(&bins[c.y >> BSHIFT], 1);
        int nlj = c.y & (NPB - 1);
        pay[2l * pj_ + 0] = make_float4(-F0, -F1, -F2, __int_as_float(nlj));
        pay[2l * pj_ + 1] = make_float4(Mj0, Mj1, Mj2, 0.f);
    }
}

__global__ __launch_bounds__(256) void bucket_pay_kernel(
    const float4* __restrict__ pay,
    const int* __restrict__ off,
    const float* __restrict__ line_load,
    const float* __restrict__ bc_disp,
    const float* __restrict__ bc_rot,
    double* __restrict__ accum)
{
    __shared__ float accF[NPB * 3];
    __shared__ float accM[NPB * 3];
    __shared__ float sm4[4];
    int b = blockIdx.x;
    for (int i = threadIdx.x; i < NPB * 3; i += 256) { accF[i] = 0.f; accM[i] = 0.f; }
    __syncthreads();

    int s0 = off[b], s1 = off[b + 1];
    int nbase = b << BSHIFT;

    for (int k = s0 + threadIdx.x; k < s1; k += 256) {
        float4 r0 = pay[2l * k + 0];
        float4 r1 = pay[2l * k + 1];
        int nl3 = __float_as_int(r0.w) * 3;
        atomicAdd(&accF[nl3 + 0], r0.x);
        atomicAdd(&accF[nl3 + 1], r0.y);
        atomicAdd(&accF[nl3 + 2], r0.z);
        atomicAdd(&accM[nl3 + 0], r1.x);
        atomicAdd(&accM[nl3 + 1], r1.y);
        atomicAdd(&accM[nl3 + 2], r1.z);
    }
    __syncthreads();

    float sqF = 0.f, sqM = 0.f, fd = 0.f, fr = 0.f;
    for (int nl = threadIdx.x; nl < NPB; nl += 256) {
        int n = nbase + nl;
        if (n < N_NODES) {
            float fdv = (bc_disp[n] < 0.5f) ? 1.f : 0.f;
            float frv = (bc_rot[n]  < 0.5f) ? 1.f : 0.f;
            float Fr0 = accF[nl * 3 + 0] + line_load[3l * n + 0];
            float Fr1 = accF[nl * 3 + 1] + line_load[3l * n + 1];
            float Fr2 = accF[nl * 3 + 2] + line_load[3l * n + 2];
            float M0 = accM[nl * 3 + 0];
            float M1 = accM[nl * 3 + 1];
            float M2 = accM[nl * 3 + 2];
            sqF += fdv * (Fr0 * Fr0 + Fr1 * Fr1 + Fr2 * Fr2);
            sqM += frv * (M0 * M0 + M1 * M1 + M2 * M2);
            fd += fdv;
            fr += frv;
        }
    }
    block_reduce_add(sqF, &accum[2], sm4);
    block_reduce_add(sqM, &accum[3], sm4);
    block_reduce_add(fd,  &accum[4], sm4);
    block_reduce_add(fr,  &accum[5], sm4);
}

__global__ void final_kernel(const double* __restrict__ accum,
                             float* __restrict__ out)
{
    double F_char = fmax(accum[0] / (double)N_ELEM, 1.0);
    double M_char = fmax(accum[1] / (double)N_ELEM, 1.0);
    double lf = accum[2] / (F_char * F_char) / fmax(accum[4] * 3.0, 1.0);
    double lm = accum[3] / (M_char * M_char) / fmax(accum[5] * 3.0, 1.0);
    out[0] = (float)(lf + lm);
}

// ---------------- fallback: round-2 index-entry path ----------------

__global__ __launch_bounds__(256) void scatter_idx_kernel(
    const int* __restrict__ conn,
    int* __restrict__ cur, unsigned int* __restrict__ entries)
{
    __shared__ int bins[NB];
    for (int i = threadIdx.x; i < NB; i += 256) bins[i] = 0;
    __syncthreads();
    int per = (N_ELEM + gridDim.x - 1) / gridDim.x;
    int e0 = blockIdx.x * per;
    int e1 = min(e0 + per, N_ELEM);
    const int2* c2 = (const int2*)conn;
    for (int e = e0 + threadIdx.x; e < e1; e += 256) {
        int2 c = c2[e];
        atomicAdd(&bins[c.x >> BSHIFT], 1);
        atomicAdd(&bins[c.y >> BSHIFT], 1);
    }
    __syncthreads();
    for (int i = threadIdx.x; i < NB; i += 256) {
        int c = bins[i];
        bins[i] = c ? atomicAdd(&cur[i], c) : 0;
    }
    __syncthreads();
    for (int e = e0 + threadIdx.x; e < e1; e += 256) {
        int2 c = c2[e];
        int p0 = atomicAdd(&bins[c.x >> BSHIFT], 1);
        entries[p0] = ((unsigned int)e << 1);
        int p1 = atomicAdd(&bins[c.y >> BSHIFT], 1);
        entries[p1] = ((unsigned int)e << 1) | 1u;
    }
}

__global__ __launch_bounds__(256) void bucket_idx_kernel(
    const float* __restrict__ pred,
    const int* __restrict__ conn,
    const float* __restrict__ dirs,
    const float* __restrict__ L_, const float* __restrict__ E_,
    const float* __restrict__ A_, const float* __restrict__ I_,
    const unsigned int* __restrict__ entries,
    const int* __restrict__ off,
    const float* __restrict__ line_load,
    const float* __restrict__ bc_disp,
    const float* __restrict__ bc_rot,
    double* __restrict__ accum)
{
    __shared__ float accF[NPB * 3];
    __shared__ float accM[NPB * 3];
    __shared__ float sm4[4];
    int b = blockIdx.x;
    for (int i = threadIdx.x; i < NPB * 3; i += 256) { accF[i] = 0.f; accM[i] = 0.f; }
    __syncthreads();
    int s0 = off[b], s1 = off[b + 1];
    const int2* c2 = (const int2*)conn;
    int nbase = b << BSHIFT;
    for (int k = s0 + threadIdx.x; k < s1; k += 256) {
        unsigned int ent = entries[k];
        int e = (int)(ent >> 1);
        int end = (int)(ent & 1u);
        int2 c = c2[e];
        float x0 = dirs[3 * e + 0], x1 = dirs[3 * e + 1], x2 = dirs[3 * e + 2];
        float F0, F1, F2, Mi0, Mi1, Mi2, Mj0, Mj1, Mj2;
        beam_full(x0, x1, x2, pred + 6l * c.x, pred + 6l * c.y,
                  L_[e], E_[e], A_[e], I_[e],
                  F0, F1, F2, Mi0, Mi1, Mi2, Mj0, Mj1, Mj2);
        int node = end ? c.y : c.x;
        float sgn = end ? -1.f : 1.f;
        float M0 = end ? Mj0 : Mi0;
        float M1 = end ? Mj1 : Mi1;
        float M2 = end ? Mj2 : Mi2;
        int nl = (node - nbase) * 3;
        atomicAdd(&accF[nl + 0], sgn * F0);
        atomicAdd(&accF[nl + 1], sgn * F1);
        atomicAdd(&accF[nl + 2], sgn * F2);
        atomicAdd(&accM[nl + 0], M0);
        atomicAdd(&accM[nl + 1], M1);
        atomicAdd(&accM[nl + 2], M2);
    }
    __syncthreads();
    float sqF = 0.f, sqM = 0.f, fd = 0.f, fr = 0.f;
    for (int nl = threadIdx.x; nl < NPB; nl += 256) {
        int n = nbase + nl;
        if (n < N_NODES) {
            float fdv = (bc_disp[n] < 0.5f) ? 1.f : 0.f;
            float frv = (bc_rot[n]  < 0.5f) ? 1.f : 0.f;
            float Fr0 = accF[nl * 3 + 0] + line_load[3l * n + 0];
            float Fr1 = accF[nl * 3 + 1] + line_load[3l * n + 1];
            float Fr2 = accF[nl * 3 + 2] + line_load[3l * n + 2];
            float M0 = accM[nl * 3 + 0];
            float M1 = accM[nl * 3 + 1];
            float M2 = accM[nl * 3 + 2];
            sqF += fdv * (Fr0 * Fr0 + Fr1 * Fr1 + Fr2 * Fr2);
            sqM += frv * (M0 * M0 + M1 * M1 + M2 * M2);
            fd += fdv;
            fr += frv;
        }
    }
    block_reduce_add(sqF, &accum[2], sm4);
    block_reduce_add(sqM, &accum[3], sm4);
    block_reduce_add(fd,  &accum[4], sm4);
    block_reduce_add(fr,  &accum[5], sm4);
}

extern "C" void kernel_launch(void* const* d_in, const int* in_sizes, int n_in,
                              void* d_out, int out_size, void* d_ws, size_t ws_size,
                              hipStream_t stream) {
    const float* pred      = (const float*)d_in[0];
    const int*   conn      = (const int*)  d_in[1];
    const float* dirs      = (const float*)d_in[2];
    const float* lens      = (const float*)d_in[3];
    const float* prop_E    = (const float*)d_in[4];
    const float* prop_A    = (const float*)d_in[5];
    const float* prop_I    = (const float*)d_in[6];
    const float* line_load = (const float*)d_in[7];
    const float* bc_disp   = (const float*)d_in[8];
    const float* bc_rot    = (const float*)d_in[9];

    double* accum = (double*)d_ws;
    int* cnt = (int*)((char*)d_ws + 1024);
    int* cur = (int*)((char*)d_ws + 8192);
    int* off = (int*)((char*)d_ws + 16384);

    if (ws_size >= WS_PAY) {
        float4* pay = (float4*)((char*)d_ws + 32768);
        hipMemsetAsync(d_ws, 0, 8192, stream);  // accum + cnt
        count_kernel<<<256, 256, 0, stream>>>(conn, lens, prop_E, prop_A, prop_I,
                                              cnt, accum);
        scan_kernel<<<1, 1024, 0, stream>>>(cnt, cur, off);
        elem_scatter_kernel<<<256, 256, 0, stream>>>(pred, conn, dirs, lens,
                                                     prop_E, prop_A, prop_I,
                                                     cur, pay);
        bucket_pay_kernel<<<NB, 256, 0, stream>>>(pay, off, line_load, bc_disp,
                                                  bc_rot, accum);
    } else {  // round-2 path (proved: ws >= 32KB + 16MB)
        unsigned int* entries = (unsigned int*)((char*)d_ws + 32768);
        hipMemsetAsync(d_ws, 0, 8192, stream);
        count_kernel<<<256, 256, 0, stream>>>(conn, lens, prop_E, prop_A, prop_I,
                                              cnt, accum);
        scan_kernel<<<1, 1024, 0, stream>>>(cnt, cur, off);
        scatter_idx_kernel<<<256, 256, 0, stream>>>(conn, cur, entries);
        bucket_idx_kernel<<<NB, 256, 0, stream>>>(pred, conn, dirs, lens, prop_E,
                                                  prop_A, prop_I, entries, off,
                                                  line_load, bc_disp, bc_rot, accum);
    }
    final_kernel<<<1, 1, 0, stream>>>(accum, (float*)d_out);
}